// Round 1
// baseline (207.818 us; speedup 1.0000x reference)
//
#include <hip/hip_runtime.h>
#include <hip/hip_bf16.h>

#define T_ROWS 8192
#define K_DIM  1024
#define N_DIM  2048
#define G_NUM  8

typedef __attribute__((ext_vector_type(8))) short short8;
typedef __attribute__((ext_vector_type(4))) float v4f;

// ---------- helpers ----------
__device__ __forceinline__ unsigned short f2bf(float x) {
  unsigned int u = __builtin_bit_cast(unsigned int, x);
  u += 0x7fffu + ((u >> 16) & 1u);   // round-to-nearest-even
  return (unsigned short)(u >> 16);
}
__device__ __forceinline__ unsigned int pk2(float a, float b) {
  return (unsigned int)f2bf(a) | ((unsigned int)f2bf(b) << 16);
}
__device__ __forceinline__ void async_cp16(const void* gsrc, void* ldst) {
  __builtin_amdgcn_global_load_lds(
      (const __attribute__((address_space(1))) void*)gsrc,
      (__attribute__((address_space(3))) void*)ldst, 16, 0, 0);
}

// ---------- kernel 1: A fp32 -> bf16 (same layout) ----------
__global__ __launch_bounds__(256) void conv_a_kernel(const float* __restrict__ A,
                                                     unsigned short* __restrict__ Ab) {
  size_t idx = (size_t)blockIdx.x * 256 + threadIdx.x;  // 8 floats per thread
  const float4* src = (const float4*)A;
  float4 v0 = src[idx * 2], v1 = src[idx * 2 + 1];
  uint4 o;
  o.x = pk2(v0.x, v0.y); o.y = pk2(v0.z, v0.w);
  o.z = pk2(v1.x, v1.y); o.w = pk2(v1.z, v1.w);
  ((uint4*)Ab)[idx] = o;
}

// ---------- kernel 2: B[g][k][n] fp32 -> Bt[g][n][k] bf16 (padded-LDS transpose) ----------
__global__ __launch_bounds__(256) void conv_b_kernel(const float* __restrict__ B,
                                                     unsigned short* __restrict__ Bt) {
  __shared__ float tile[64][65];   // +1 pad: stride 65 dwords == 1 mod 32 -> conflict-free
  const int bid = blockIdx.x;
  const int nt = bid & 31;          // N/64
  const int kt = (bid >> 5) & 15;   // K/64
  const int g  = bid >> 9;          // G
  const int t  = threadIdx.x;
  const int c4 = t & 15;            // float4 column within 64-wide n tile
  const int r  = t >> 4;            // 0..15

  const float* src = B + ((size_t)g * K_DIM + (size_t)kt * 64) * N_DIM + (size_t)nt * 64;
#pragma unroll
  for (int i = 0; i < 4; ++i) {
    int k = r + i * 16;
    float4 v = *(const float4*)(src + (size_t)k * N_DIM + c4 * 4);
    tile[k][c4 * 4 + 0] = v.x; tile[k][c4 * 4 + 1] = v.y;
    tile[k][c4 * 4 + 2] = v.z; tile[k][c4 * 4 + 3] = v.w;
  }
  __syncthreads();
  unsigned short* dst = Bt + ((size_t)g * N_DIM + (size_t)nt * 64) * K_DIM + (size_t)kt * 64;
#pragma unroll
  for (int i = 0; i < 2; ++i) {
    int idx = t + i * 256;
    int n = idx >> 3;        // 0..63
    int seg = idx & 7;       // 8 k's per 16B segment
    unsigned int u0 = pk2(tile[seg * 8 + 0][n], tile[seg * 8 + 1][n]);
    unsigned int u1 = pk2(tile[seg * 8 + 2][n], tile[seg * 8 + 3][n]);
    unsigned int u2 = pk2(tile[seg * 8 + 4][n], tile[seg * 8 + 5][n]);
    unsigned int u3 = pk2(tile[seg * 8 + 6][n], tile[seg * 8 + 7][n]);
    uint4 o; o.x = u0; o.y = u1; o.z = u2; o.w = u3;
    *(uint4*)(dst + (size_t)n * K_DIM + seg * 8) = o;
  }
}

// ---------- kernel 3: grouped bf16 MFMA GEMM, 128x128 tile, BK=64 ----------
// LDS layout (A and B identical): [128 rows][8 chunks of 16B], data for (row,ch)
// stored at physical chunk (ch ^ (row&7)) -- XOR swizzle keeps global_load_lds's
// lane-contiguous constraint AND makes fragment ds_read_b128 2-way (free).
__global__ __launch_bounds__(256) void gemm_kernel(const unsigned short* __restrict__ Ab,
                                                   const unsigned short* __restrict__ Btb,
                                                   const int* __restrict__ offs,
                                                   float* __restrict__ out) {
  __shared__ unsigned short As[128 * 64];
  __shared__ unsigned short Bs[128 * 64];
  const int t = threadIdx.x;
  const int n0 = blockIdx.x * 128;
  const int mslot = blockIdx.y;

  // map slot -> (group, row tile); uniform across block
  int prev = 0, cum = 0, row0 = 0, row_end = 0, g = 0, found = 0;
#pragma unroll
  for (int gg = 0; gg < G_NUM; ++gg) {
    int e = offs[gg];
    int tiles = (e - prev + 127) >> 7;
    if (!found && mslot < cum + tiles) {
      found = 1; g = gg; row0 = prev + (mslot - cum) * 128; row_end = e;
    }
    cum += tiles;
    prev = e;
  }
  if (!found) return;

  const int lane = t & 63;
  const int wv = t >> 6;
  const int wm = wv & 1;        // 2x2 wave grid, each wave does 64x64
  const int wn = wv >> 1;
  const int srcChunk = (t & 7) ^ ((t >> 3) & 7);  // XOR swizzle on the load side

  v4f acc[4][4];
#pragma unroll
  for (int i = 0; i < 4; ++i)
#pragma unroll
    for (int j = 0; j < 4; ++j)
#pragma unroll
      for (int r = 0; r < 4; ++r) acc[i][j][r] = 0.0f;

  const size_t bRow = (size_t)g * N_DIM;

  for (int k0 = 0; k0 < K_DIM; k0 += 64) {
    __syncthreads();
#pragma unroll
    for (int c = 0; c < 4; ++c) {
      int rl = c * 32 + (t >> 3);
      int rA = row0 + rl; if (rA > T_ROWS - 1) rA = T_ROWS - 1;  // tail clamp (masked at store)
      async_cp16(Ab + (size_t)rA * K_DIM + k0 + srcChunk * 8,
                 (char*)As + c * 4096 + t * 16);
      int nG = n0 + rl;
      async_cp16(Btb + (bRow + nG) * K_DIM + k0 + srcChunk * 8,
                 (char*)Bs + c * 4096 + t * 16);
    }
    __syncthreads();
#pragma unroll
    for (int ks = 0; ks < 2; ++ks) {
      short8 a[4], b[4];
      int chBase = (lane >> 4) + ks * 4;
      int chPhys = chBase ^ (lane & 7);
#pragma unroll
      for (int im = 0; im < 4; ++im) {
        int row = wm * 64 + im * 16 + (lane & 15);
        a[im] = *(const short8*)((const char*)As + row * 128 + chPhys * 16);
      }
#pragma unroll
      for (int in = 0; in < 4; ++in) {
        int row = wn * 64 + in * 16 + (lane & 15);
        b[in] = *(const short8*)((const char*)Bs + row * 128 + chPhys * 16);
      }
#pragma unroll
      for (int im = 0; im < 4; ++im)
#pragma unroll
        for (int in = 0; in < 4; ++in)
          acc[im][in] = __builtin_amdgcn_mfma_f32_16x16x32_bf16(a[im], b[in], acc[im][in], 0, 0, 0);
    }
  }

  // epilogue: C/D layout col=lane&15, row=(lane>>4)*4+reg (m89/m91-verified)
  const int colBase = n0 + wn * 64 + (lane & 15);
  const int rowBase = row0 + wm * 64 + ((lane >> 4) << 2);
#pragma unroll
  for (int im = 0; im < 4; ++im) {
#pragma unroll
    for (int in = 0; in < 4; ++in) {
      int c = colBase + in * 16;
#pragma unroll
      for (int r = 0; r < 4; ++r) {
        int rr = rowBase + im * 16 + r;
        if (rr < row_end) out[(size_t)rr * N_DIM + c] = acc[im][in][r];
      }
    }
  }
}

// ---------- fallback (only if workspace too small): fp32 vector GEMM ----------
__global__ __launch_bounds__(256) void fallback_kernel(const float* __restrict__ A,
                                                       const float* __restrict__ B,
                                                       const int* __restrict__ offs,
                                                       float* __restrict__ out) {
  int r = blockIdx.y;
  int c = blockIdx.x * 256 + threadIdx.x;
  int g = 0;
#pragma unroll
  for (int i = 0; i < G_NUM; ++i) g += (offs[i] <= r);  // searchsorted side='right'
  const float* a = A + (size_t)r * K_DIM;
  const float* b = B + (size_t)g * K_DIM * N_DIM + c;
  float s = 0.f;
  for (int k = 0; k < K_DIM; ++k) s += a[k] * b[(size_t)k * N_DIM];
  out[(size_t)r * N_DIM + c] = s;
}

extern "C" void kernel_launch(void* const* d_in, const int* in_sizes, int n_in,
                              void* d_out, int out_size, void* d_ws, size_t ws_size,
                              hipStream_t stream) {
  const float* A = (const float*)d_in[0];
  const float* B = (const float*)d_in[1];
  const int* offs = (const int*)d_in[2];
  float* out = (float*)d_out;

  size_t need = ((size_t)T_ROWS * K_DIM + (size_t)G_NUM * K_DIM * N_DIM) * 2;
  if (ws_size < need) {
    dim3 grid(N_DIM / 256, T_ROWS);
    fallback_kernel<<<grid, 256, 0, stream>>>(A, B, offs, out);
    return;
  }
  unsigned short* Ab = (unsigned short*)d_ws;
  unsigned short* Btb = Ab + (size_t)T_ROWS * K_DIM;

  conv_a_kernel<<<(T_ROWS * K_DIM / 8) / 256, 256, 0, stream>>>(A, Ab);
  conv_b_kernel<<<G_NUM * (K_DIM / 64) * (N_DIM / 64), 256, 0, stream>>>(B, Btb);
  dim3 grid(N_DIM / 128, T_ROWS / 128 + G_NUM);
  gemm_kernel<<<grid, 256, 0, stream>>>(Ab, Btb, offs, out);
}

// Round 2
// 191.548 us; speedup vs baseline: 1.0849x; 1.0849x over previous
//
#include <hip/hip_runtime.h>
#include <hip/hip_bf16.h>

#define T_ROWS 8192
#define K_DIM  1024
#define N_DIM  2048
#define G_NUM  8
#define CONVA_BLOCKS 4096   // (T*K/8)/256
#define CONVB_BLOCKS 4096   // G*(K/64)*(N/64)

typedef __attribute__((ext_vector_type(8))) short short8;
typedef __attribute__((ext_vector_type(4))) float v4f;

// ---------- helpers ----------
__device__ __forceinline__ unsigned short f2bf(float x) {
  unsigned int u = __builtin_bit_cast(unsigned int, x);
  u += 0x7fffu + ((u >> 16) & 1u);   // round-to-nearest-even
  return (unsigned short)(u >> 16);
}
__device__ __forceinline__ unsigned int pk2(float a, float b) {
  return (unsigned int)f2bf(a) | ((unsigned int)f2bf(b) << 16);
}
__device__ __forceinline__ void async_cp16(const void* gsrc, void* ldst) {
  __builtin_amdgcn_global_load_lds(
      (const __attribute__((address_space(1))) void*)gsrc,
      (__attribute__((address_space(3))) void*)ldst, 16, 0, 0);
}

// ---------- fused convert: blocks [0,4096) do A, [4096,8192) do B-transpose ----------
__global__ __launch_bounds__(256) void conv_fused(const float* __restrict__ A,
                                                  const float* __restrict__ B,
                                                  unsigned short* __restrict__ Ab,
                                                  unsigned short* __restrict__ Bt) {
  __shared__ float tile[64][65];   // only used by the B path; +1 pad -> conflict-free
  int bid = blockIdx.x;
  const int t = threadIdx.x;

  if (bid < CONVA_BLOCKS) {
    // ---- A fp32 -> bf16, same layout, 8 floats/thread ----
    size_t idx = (size_t)bid * 256 + t;
    const float4* src = (const float4*)A;
    float4 v0 = src[idx * 2], v1 = src[idx * 2 + 1];
    uint4 o;
    o.x = pk2(v0.x, v0.y); o.y = pk2(v0.z, v0.w);
    o.z = pk2(v1.x, v1.y); o.w = pk2(v1.z, v1.w);
    ((uint4*)Ab)[idx] = o;
    return;
  }
  bid -= CONVA_BLOCKS;
  // ---- B[g][k][n] fp32 -> Bt[g][n][k] bf16 via padded-LDS 64x64 transpose ----
  const int nt = bid & 31;          // N/64
  const int kt = (bid >> 5) & 15;   // K/64
  const int g  = bid >> 9;          // G
  const int c4 = t & 15;
  const int r  = t >> 4;

  const float* src = B + ((size_t)g * K_DIM + (size_t)kt * 64) * N_DIM + (size_t)nt * 64;
#pragma unroll
  for (int i = 0; i < 4; ++i) {
    int k = r + i * 16;
    float4 v = *(const float4*)(src + (size_t)k * N_DIM + c4 * 4);
    tile[k][c4 * 4 + 0] = v.x; tile[k][c4 * 4 + 1] = v.y;
    tile[k][c4 * 4 + 2] = v.z; tile[k][c4 * 4 + 3] = v.w;
  }
  __syncthreads();
  unsigned short* dst = Bt + ((size_t)g * N_DIM + (size_t)nt * 64) * K_DIM + (size_t)kt * 64;
#pragma unroll
  for (int i = 0; i < 2; ++i) {
    int idx = t + i * 256;
    int n = idx >> 3;
    int seg = idx & 7;
    unsigned int u0 = pk2(tile[seg * 8 + 0][n], tile[seg * 8 + 1][n]);
    unsigned int u1 = pk2(tile[seg * 8 + 2][n], tile[seg * 8 + 3][n]);
    unsigned int u2 = pk2(tile[seg * 8 + 4][n], tile[seg * 8 + 5][n]);
    unsigned int u3 = pk2(tile[seg * 8 + 6][n], tile[seg * 8 + 7][n]);
    uint4 o; o.x = u0; o.y = u1; o.z = u2; o.w = u3;
    *(uint4*)(dst + (size_t)n * K_DIM + seg * 8) = o;
  }
}

// ---------- grouped bf16 MFMA GEMM, 128x128 tile, BK=64, peeled + hoisted ----------
__global__ __launch_bounds__(256) void gemm_kernel(const unsigned short* __restrict__ Ab,
                                                   const unsigned short* __restrict__ Btb,
                                                   const int* __restrict__ offs,
                                                   float* __restrict__ out) {
  __shared__ unsigned short As[128 * 64];
  __shared__ unsigned short Bs[128 * 64];
  const int t = threadIdx.x;
  const int n0 = blockIdx.x * 128;
  const int mslot = blockIdx.y;

  // slot -> (group, row tile); wave-uniform
  int prev = 0, cum = 0, row0 = 0, row_end = 0, g = 0, found = 0;
#pragma unroll
  for (int gg = 0; gg < G_NUM; ++gg) {
    int e = offs[gg];
    int tiles = (e - prev + 127) >> 7;
    if (!found && mslot < cum + tiles) {
      found = 1; g = gg; row0 = prev + (mslot - cum) * 128; row_end = e;
    }
    cum += tiles;
    prev = e;
  }
  if (!found) return;

  const int lane = t & 63;
  const int wv = t >> 6;
  const int wm = wv & 1;
  const int wn = wv >> 1;
  const int srcChunk = (t & 7) ^ ((t >> 3) & 7);  // XOR swizzle, matches frag-read side

  // hoisted global source pointers (k0-invariant) and LDS destinations
  const unsigned short* aSrc[4];
  const unsigned short* bSrc[4];
  char* aDst[4];
  char* bDst[4];
#pragma unroll
  for (int c = 0; c < 4; ++c) {
    int rl = c * 32 + (t >> 3);
    int rA = row0 + rl; if (rA > T_ROWS - 1) rA = T_ROWS - 1;  // tail clamp (store-masked)
    aSrc[c] = Ab + (size_t)rA * K_DIM + srcChunk * 8;
    bSrc[c] = Btb + ((size_t)g * N_DIM + n0 + rl) * K_DIM + srcChunk * 8;
    aDst[c] = (char*)As + c * 4096 + t * 16;
    bDst[c] = (char*)Bs + c * 4096 + t * 16;
  }

  v4f acc[4][4];
#pragma unroll
  for (int i = 0; i < 4; ++i)
#pragma unroll
    for (int j = 0; j < 4; ++j)
#pragma unroll
      for (int r = 0; r < 4; ++r) acc[i][j][r] = 0.0f;

  // peel: prefetch k0 = 0
#pragma unroll
  for (int c = 0; c < 4; ++c) {
    async_cp16(aSrc[c], aDst[c]);
    async_cp16(bSrc[c], bDst[c]);
  }

  for (int k0 = 0; k0 < K_DIM; k0 += 64) {
    __syncthreads();   // implicit vmcnt(0) drain -> LDS tiles ready
#pragma unroll
    for (int ks = 0; ks < 2; ++ks) {
      short8 a[4], b[4];
      int chBase = (lane >> 4) + ks * 4;
      int chPhys = chBase ^ (lane & 7);
#pragma unroll
      for (int im = 0; im < 4; ++im) {
        int row = wm * 64 + im * 16 + (lane & 15);
        a[im] = *(const short8*)((const char*)As + row * 128 + chPhys * 16);
      }
#pragma unroll
      for (int in = 0; in < 4; ++in) {
        int row = wn * 64 + in * 16 + (lane & 15);
        b[in] = *(const short8*)((const char*)Bs + row * 128 + chPhys * 16);
      }
#pragma unroll
      for (int im = 0; im < 4; ++im)
#pragma unroll
        for (int in = 0; in < 4; ++in)
          acc[im][in] = __builtin_amdgcn_mfma_f32_16x16x32_bf16(a[im], b[in], acc[im][in], 0, 0, 0);
    }
    if (k0 + 64 < K_DIM) {
      __syncthreads();   // everyone done reading LDS
      int koff = k0 + 64;
#pragma unroll
      for (int c = 0; c < 4; ++c) {
        async_cp16(aSrc[c] + koff, aDst[c]);
        async_cp16(bSrc[c] + koff, bDst[c]);
      }
    }
  }

  // epilogue: C/D layout col=lane&15, row=(lane>>4)*4+reg
  const int colBase = n0 + wn * 64 + (lane & 15);
  const int rowBase = row0 + wm * 64 + ((lane >> 4) << 2);
#pragma unroll
  for (int im = 0; im < 4; ++im) {
#pragma unroll
    for (int in = 0; in < 4; ++in) {
      int c = colBase + in * 16;
#pragma unroll
      for (int r = 0; r < 4; ++r) {
        int rr = rowBase + im * 16 + r;
        if (rr < row_end) out[(size_t)rr * N_DIM + c] = acc[im][in][r];
      }
    }
  }
}

// ---------- fallback (workspace too small): fp32 vector GEMM ----------
__global__ __launch_bounds__(256) void fallback_kernel(const float* __restrict__ A,
                                                       const float* __restrict__ B,
                                                       const int* __restrict__ offs,
                                                       float* __restrict__ out) {
  int r = blockIdx.y;
  int c = blockIdx.x * 256 + threadIdx.x;
  int g = 0;
#pragma unroll
  for (int i = 0; i < G_NUM; ++i) g += (offs[i] <= r);
  const float* a = A + (size_t)r * K_DIM;
  const float* b = B + (size_t)g * K_DIM * N_DIM + c;
  float s = 0.f;
  for (int k = 0; k < K_DIM; ++k) s += a[k] * b[(size_t)k * N_DIM];
  out[(size_t)r * N_DIM + c] = s;
}

extern "C" void kernel_launch(void* const* d_in, const int* in_sizes, int n_in,
                              void* d_out, int out_size, void* d_ws, size_t ws_size,
                              hipStream_t stream) {
  const float* A = (const float*)d_in[0];
  const float* B = (const float*)d_in[1];
  const int* offs = (const int*)d_in[2];
  float* out = (float*)d_out;

  size_t need = ((size_t)T_ROWS * K_DIM + (size_t)G_NUM * K_DIM * N_DIM) * 2;
  if (ws_size < need) {
    dim3 grid(N_DIM / 256, T_ROWS);
    fallback_kernel<<<grid, 256, 0, stream>>>(A, B, offs, out);
    return;
  }
  unsigned short* Ab = (unsigned short*)d_ws;
  unsigned short* Btb = Ab + (size_t)T_ROWS * K_DIM;

  conv_fused<<<CONVA_BLOCKS + CONVB_BLOCKS, 256, 0, stream>>>(A, B, Ab, Btb);
  dim3 grid(N_DIM / 128, T_ROWS / 128 + G_NUM);
  gemm_kernel<<<grid, 256, 0, stream>>>(Ab, Btb, offs, out);
}